// Round 1
// baseline (912.961 us; speedup 1.0000x reference)
//
#include <hip/hip_runtime.h>
#include <cstddef>

#define EPSF 1e-12f

constexpr int Bc = 16, Dc = 128, Lc = 4096, Kc = 4096;
constexpr int Nc = Bc * Lc;   // 65536

// ---------------------------------------------------------------------------
// Kernel 1: per-vector inverse norms of x.  x is [B][D][L]; vector n=(b,l)
// is strided by L floats.  Each thread handles 4 consecutive l (float4 loads,
// coalesced across the wave).
// ---------------------------------------------------------------------------
__global__ void k_xnorm(const float* __restrict__ x, float* __restrict__ invn) {
    int t  = blockIdx.x * blockDim.x + threadIdx.x;   // handles n = 4t .. 4t+3
    int n0 = t << 2;
    int b  = n0 >> 12;              // L = 4096
    int l  = n0 & (Lc - 1);
    const float4* p = (const float4*)(x + (size_t)b * Dc * Lc + l);
    float sx = 0.f, sy = 0.f, sz = 0.f, sw = 0.f;
    #pragma unroll 16
    for (int d = 0; d < Dc; ++d) {
        float4 v = p[d * (Lc / 4)];
        sx += v.x * v.x; sy += v.y * v.y; sz += v.z * v.z; sw += v.w * v.w;
    }
    float4 r;
    r.x = 1.f / fmaxf(sqrtf(sx), EPSF);
    r.y = 1.f / fmaxf(sqrtf(sy), EPSF);
    r.z = 1.f / fmaxf(sqrtf(sz), EPSF);
    r.w = 1.f / fmaxf(sqrtf(sw), EPSF);
    ((float4*)invn)[t] = r;
}

// ---------------------------------------------------------------------------
// Kernel 2: normalize embeddings -> cbn [K][D] (for the gather) and
// cbnT [D][K] (transposed, for coalesced LDS staging in k_argmax).
// One wave per codebook row.  Also zero-inits the loss accumulator.
// ---------------------------------------------------------------------------
__global__ void k_cbnorm(const float* __restrict__ emb, float* __restrict__ cbn,
                         float* __restrict__ cbnT, float* __restrict__ lacc) {
    int k    = (blockIdx.x << 2) + (threadIdx.x >> 6);
    int lane = threadIdx.x & 63;
    float2 v = ((const float2*)(emb + (size_t)k * Dc))[lane];
    float s = v.x * v.x + v.y * v.y;
    #pragma unroll
    for (int off = 32; off > 0; off >>= 1) s += __shfl_down(s, off);
    s = __shfl(s, 0);
    float inv = 1.f / fmaxf(sqrtf(s), EPSF);
    v.x *= inv; v.y *= inv;
    ((float2*)(cbn + (size_t)k * Dc))[lane] = v;
    cbnT[(size_t)(2 * lane)     * Kc + k] = v.x;
    cbnT[(size_t)(2 * lane + 1) * Kc + k] = v.y;
    if (blockIdx.x == 0 && threadIdx.x == 0) *lacc = 0.f;
}

// ---------------------------------------------------------------------------
// Kernel 3: the hot one.  Per block: 128 query vectors (one b, contiguous l),
// argmax over all K=4096 codes.  Tiled fp32 SGEMM: k-tiles of 128 codes,
// D in 2 chunks of 64, 8x8 register micro-tile per thread (split layout so
// LDS float4 reads are broadcast / 2-way only).  After each k-tile the 64
// accumulators fold into a running (max, argmax) per row; tie-break = first
// (smallest) index to match jnp.argmax.
// ---------------------------------------------------------------------------
__global__ __launch_bounds__(256, 2)
void k_argmax(const float* __restrict__ x, const float* __restrict__ invn,
              const float* __restrict__ cbnT, int* __restrict__ idx_out,
              float* __restrict__ lossacc) {
    constexpr int BD = 64;
    __shared__ float As[BD][128];   // [d][n]  32 KB
    __shared__ float Bs[BD][128];   // [d][k]  32 KB
    __shared__ float bsum;

    const int tid = threadIdx.x;
    const int tx  = tid & 15;
    const int ty  = tid >> 4;
    const int n0  = blockIdx.x * 128;
    const int b   = n0 >> 12;            // tile never straddles b (128 | 4096)
    const int l0  = n0 & (Lc - 1);
    const float* xb = x + (size_t)b * Dc * Lc + l0;

    const int lc = (tid & 31) << 2;      // staging column  0..124
    const int lr = tid >> 5;             // staging row base 0..7

    // invnorms for this thread's staging columns (constant for whole kernel)
    const float4 w = *(const float4*)(invn + n0 + lc);

    float bestv[8];
    int   bestk[8];
    #pragma unroll
    for (int r = 0; r < 8; ++r) { bestv[r] = -3.0e38f; bestk[r] = 0; }

    for (int k0 = 0; k0 < Kc; k0 += 128) {
        float acc[8][8];
        #pragma unroll
        for (int r = 0; r < 8; ++r)
            #pragma unroll
            for (int c = 0; c < 8; ++c) acc[r][c] = 0.f;

        for (int d0 = 0; d0 < Dc; d0 += BD) {
            __syncthreads();   // protect LDS from readers of previous chunk
            #pragma unroll
            for (int i = 0; i < 8; ++i) {
                int dd = lr + (i << 3);
                float4 v = *(const float4*)(xb + (size_t)(d0 + dd) * Lc + lc);
                v.x *= w.x; v.y *= w.y; v.z *= w.z; v.w *= w.w;
                *(float4*)&As[dd][lc] = v;
                *(float4*)&Bs[dd][lc] =
                    *(const float4*)(cbnT + (size_t)(d0 + dd) * Kc + k0 + lc);
            }
            __syncthreads();
            #pragma unroll 8
            for (int dd = 0; dd < BD; ++dd) {
                float4 a0 = *(const float4*)&As[dd][ty << 2];
                float4 a1 = *(const float4*)&As[dd][64 + (ty << 2)];
                float4 q0 = *(const float4*)&Bs[dd][tx << 2];
                float4 q1 = *(const float4*)&Bs[dd][64 + (tx << 2)];
                float a[8]  = {a0.x, a0.y, a0.z, a0.w, a1.x, a1.y, a1.z, a1.w};
                float bv[8] = {q0.x, q0.y, q0.z, q0.w, q1.x, q1.y, q1.z, q1.w};
                #pragma unroll
                for (int r = 0; r < 8; ++r)
                    #pragma unroll
                    for (int c = 0; c < 8; ++c)
                        acc[r][c] = fmaf(a[r], bv[c], acc[r][c]);
            }
        }
        // fold into running best; c iterates in increasing k so strict '>'
        // keeps the first (smallest) index on ties, matching jnp.argmax
        #pragma unroll
        for (int c = 0; c < 8; ++c) {
            int kk = k0 + ((c < 4) ? ((tx << 2) + c) : (64 + (tx << 2) + c - 4));
            #pragma unroll
            for (int r = 0; r < 8; ++r) {
                if (acc[r][c] > bestv[r]) { bestv[r] = acc[r][c]; bestk[r] = kk; }
            }
        }
    }

    // cross-thread reduction over the 16 tx slices per row (reuse LDS)
    __syncthreads();
    float* redv = &As[0][0];          // 128*16 floats
    int*   redk = (int*)&Bs[0][0];
    if (tid == 0) bsum = 0.f;
    #pragma unroll
    for (int r = 0; r < 8; ++r) {
        int n = (r < 4) ? ((ty << 2) + r) : (64 + (ty << 2) + r - 4);
        redv[n * 16 + tx] = bestv[r];
        redk[n * 16 + tx] = bestk[r];
    }
    __syncthreads();
    if (tid < 128) {
        float v  = redv[tid * 16];
        int   kk = redk[tid * 16];
        #pragma unroll
        for (int j = 1; j < 16; ++j) {
            float vj = redv[tid * 16 + j];
            int   kj = redk[tid * 16 + j];
            if (vj > v || (vj == v && kj < kk)) { v = vj; kk = kj; }
        }
        idx_out[n0 + tid] = kk;
        atomicAdd(&bsum, v);
    }
    __syncthreads();
    if (tid == 0) atomicAdd(lossacc, bsum);
}

// ---------------------------------------------------------------------------
// Kernel 4: out[b][d][l] = cbn[idx[n]][d]  (straight-through value == q).
// 64 l per block; writes coalesced 256B runs, gathers hit L1/L2 (cbn = 2MB).
// ---------------------------------------------------------------------------
__global__ void k_gather(const float* __restrict__ cbn, const int* __restrict__ idx,
                         float* __restrict__ out) {
    __shared__ int sidx[64];
    int n0 = blockIdx.x << 6;
    int b  = n0 >> 12;
    int l0 = n0 & (Lc - 1);
    if (threadIdx.x < 64) sidx[threadIdx.x] = idx[n0 + threadIdx.x];
    __syncthreads();
    int t = threadIdx.x;
    #pragma unroll
    for (int i = 0; i < 32; ++i) {
        int p = t + (i << 8);
        int d = p >> 6;
        int l = p & 63;
        out[(size_t)b * Dc * Lc + (size_t)d * Lc + l0 + l] =
            cbn[(size_t)sidx[l] * Dc + d];
    }
}

// ---------------------------------------------------------------------------
// Kernel 5: loss = mean(COMMITMENT*e_loss + q_loss) = 2 - 2*mean(maxsim)
// ---------------------------------------------------------------------------
__global__ void k_loss(const float* __restrict__ lacc, float* __restrict__ oloss) {
    *oloss = 2.0f - 2.0f * (*lacc) / (float)Nc;
}

// ---------------------------------------------------------------------------
extern "C" void kernel_launch(void* const* d_in, const int* in_sizes, int n_in,
                              void* d_out, int out_size, void* d_ws, size_t ws_size,
                              hipStream_t stream) {
    const float* x   = (const float*)d_in[0];   // [16][128][4096] fp32
    const float* emb = (const float*)d_in[1];   // [4096][128] fp32
    float* out = (float*)d_out;                 // 16*128*4096 out + 1 loss

    char*  ws   = (char*)d_ws;
    float* cbn  = (float*)ws;                            // 2 MB
    float* cbnT = (float*)(ws + (2u << 20));             // 2 MB
    float* invn = (float*)(ws + (4u << 20));             // 256 KB
    int*   idx  = (int*)  (ws + (4u << 20) + (256u << 10)); // 256 KB
    float* lacc = (float*)(ws + (4u << 20) + (512u << 10)); // 4 B

    k_xnorm <<<Nc / 4 / 256, 256, 0, stream>>>(x, invn);
    k_cbnorm<<<Kc / 4,       256, 0, stream>>>(emb, cbn, cbnT, lacc);
    k_argmax<<<Nc / 128,     256, 0, stream>>>(x, invn, cbnT, idx, lacc);
    k_gather<<<Nc / 64,      256, 0, stream>>>(cbn, idx, out);
    k_loss  <<<1, 1,         0, stream>>>(lacc, out + (size_t)Bc * Dc * Lc);
}